// Round 2
// baseline (269.759 us; speedup 1.0000x reference)
//
#include <hip/hip_runtime.h>
#include <hip/hip_bf16.h>

// ---------------------------------------------------------------------------
// RRN forward, MI355X. Precision-hardened decomposition:
//   K1: A32 = hidden@Wf1[:,:H].T + bf1 ; B32 = hidden@Wf1[:,H:].T  (fp32!)
//       + split Wf2 -> Whi (fp16) + Wlo (fp16, x4096)
//   K2: S[j,n] = sum_i relu( sum_k relu(A32[i,k]+B32[j,k]) * Wf2[n,k] + bf2[n] )
//       h computed in fp32, rounded ONCE to fp16 (RTN, error random over i);
//       W via hi/lo split (2 MFMA chains) -> no i-systematic error terms.
//   K3: sum_messages[j,m] = sum_n Wf3[m,n]*S[j,n] + N*bf3[m]
//   K4: fused tail: g_mlp -> LSTM (1 step) -> o MLP -> all 4 outputs (fp32)
// ---------------------------------------------------------------------------

#define NN   512
#define HH   128
#define F1D  256
#define F2D  256
#define MSGD 128
#define OUTD 64

typedef _Float16 half_t;
typedef _Float16 half8 __attribute__((ext_vector_type(8)));
typedef float float4_t __attribute__((ext_vector_type(4)));
typedef float float8_t __attribute__((ext_vector_type(8)));

__device__ __forceinline__ float sigmoidf_(float x) {
    return 1.0f / (1.0f + __expf(-x));
}

// ---------------- K1: projections (fp32 out) + Wf2 hi/lo split ----------------
// 128 blocks x 256 threads, 4 rows each.
__global__ void k1_proj(const float* __restrict__ hidden,
                        const float* __restrict__ Wf1,
                        const float* __restrict__ bf1,
                        const float* __restrict__ Wf2,
                        float* __restrict__ A32,
                        float* __restrict__ B32,
                        half_t* __restrict__ Whi,
                        half_t* __restrict__ Wlo) {
    __shared__ float hid[4][HH];
    const int t = threadIdx.x;
    const int i0 = blockIdx.x * 4;
    for (int q = t; q < 4 * HH; q += 256)
        hid[q >> 7][q & 127] = hidden[(i0 + (q >> 7)) * HH + (q & 127)];
    __syncthreads();

    float accA[4], accB[4];
    const float b = bf1[t];
#pragma unroll
    for (int r = 0; r < 4; ++r) { accA[r] = b; accB[r] = 0.0f; }

    const float* wr = Wf1 + t * 256;
    for (int k = 0; k < HH; k += 4) {
        float4_t wa = *(const float4_t*)(wr + k);
        float4_t wb = *(const float4_t*)(wr + HH + k);
#pragma unroll
        for (int r = 0; r < 4; ++r) {
            const float* hp = &hid[r][k];
            accA[r] += wa[0]*hp[0] + wa[1]*hp[1] + wa[2]*hp[2] + wa[3]*hp[3];
            accB[r] += wb[0]*hp[0] + wb[1]*hp[1] + wb[2]*hp[2] + wb[3]*hp[3];
        }
    }
#pragma unroll
    for (int r = 0; r < 4; ++r) {
        A32[(i0 + r) * F1D + t] = accA[r];
        B32[(i0 + r) * F1D + t] = accB[r];
    }
    // split Wf2 (65536 elems): 512 per block
    for (int q = t; q < 512; q += 256) {
        int idx = blockIdx.x * 512 + q;
        float wv = Wf2[idx];
        half_t hi = (half_t)wv;
        Whi[idx] = hi;
        Wlo[idx] = (half_t)((wv - (float)hi) * 4096.0f);
    }
}

// ---------------- K2: pairwise MLP core ----------------
// grid (8 i-chunks, 32 j-tiles) x 512 threads (8 waves), 1 block/CU.
// wave w owns n-range [w*32, w*32+32) (nt=0,1). M-tile = 16 j's. K = 256.
__global__ __launch_bounds__(512, 2)
void k2_pairwise(const float* __restrict__ A32,
                 const float* __restrict__ B32,
                 const half_t* __restrict__ Whi,
                 const half_t* __restrict__ Wlo,
                 const float* __restrict__ bf2,
                 float* __restrict__ S) {
    __shared__ float Alds[64 * F1D];   // 64 KB: this block's 64 A-rows

    const int tid = threadIdx.x;
    const int lane = tid & 63;
    const int w = tid >> 6;           // wave 0..7
    const int l15 = lane & 15;
    const int g4 = lane >> 4;         // 0..3
    const int j0 = blockIdx.y * 16;
    const int i0 = blockIdx.x * 64;

    // stage A rows for this i-chunk
    {
        const float4_t* src = (const float4_t*)(A32 + (size_t)i0 * F1D);
        float4_t* dst = (float4_t*)Alds;
        for (int q = tid; q < 64 * F1D / 4; q += 512) dst[q] = src[q];
    }

    // persistent W fragments: B-operand, n = w*32 + nt*16 + l15, k = ks*32 + g4*8 + e
    half8 Wh[2][8], Wl[2][8];
#pragma unroll
    for (int nt = 0; nt < 2; ++nt)
#pragma unroll
        for (int ks = 0; ks < 8; ++ks) {
            const size_t off = (size_t)(w*32 + nt*16 + l15) * F1D + ks*32 + g4*8;
            Wh[nt][ks] = *(const half8*)(Whi + off);
            Wl[nt][ks] = *(const half8*)(Wlo + off);
        }

    // persistent B' fragments (fp32) for this block's 16 j's
    float8_t Bk[8];
#pragma unroll
    for (int ks = 0; ks < 8; ++ks)
        Bk[ks] = *(const float8_t*)(B32 + (size_t)(j0 + l15) * F1D + ks*32 + g4*8);

    float b2v[2];
#pragma unroll
    for (int nt = 0; nt < 2; ++nt) b2v[nt] = bf2[w*32 + nt*16 + l15];

    float4_t acc[2];
#pragma unroll
    for (int nt = 0; nt < 2; ++nt)
#pragma unroll
        for (int r = 0; r < 4; ++r) acc[nt][r] = 0.0f;

    __syncthreads();

    for (int io = 0; io < 64; ++io) {
        const float* Ar = Alds + io * F1D;

        float4_t C[2], Cl[2];
#pragma unroll
        for (int nt = 0; nt < 2; ++nt)
#pragma unroll
            for (int r = 0; r < 4; ++r) { C[nt][r] = 0.0f; Cl[nt][r] = 0.0f; }

#pragma unroll
        for (int ks = 0; ks < 8; ++ks) {
            float8_t a = *(const float8_t*)(Ar + ks*32 + g4*8);
            float8_t s = a + Bk[ks];
            half8 hf;
#pragma unroll
            for (int e = 0; e < 8; ++e) {
                float v = fmaxf(s[e], 0.0f);   // relu in fp32
                hf[e] = (half_t)v;             // single RTN rounding
            }
            C[0]  = __builtin_amdgcn_mfma_f32_16x16x32_f16(hf, Wh[0][ks], C[0], 0, 0, 0);
            C[1]  = __builtin_amdgcn_mfma_f32_16x16x32_f16(hf, Wh[1][ks], C[1], 0, 0, 0);
            Cl[0] = __builtin_amdgcn_mfma_f32_16x16x32_f16(hf, Wl[0][ks], Cl[0], 0, 0, 0);
            Cl[1] = __builtin_amdgcn_mfma_f32_16x16x32_f16(hf, Wl[1][ks], Cl[1], 0, 0, 0);
        }
        // h2 = relu(C + Clo/4096 + bf2), accumulate over i
#pragma unroll
        for (int nt = 0; nt < 2; ++nt) {
#pragma unroll
            for (int r = 0; r < 4; ++r) {
                float v = fmaf(Cl[nt][r], 2.44140625e-4f, C[nt][r]) + b2v[nt];
                acc[nt][r] += fmaxf(v, 0.0f);
            }
        }
    }

    // C layout: col = l15 (n), row = g4*4 + r (jj)
#pragma unroll
    for (int nt = 0; nt < 2; ++nt)
#pragma unroll
        for (int r = 0; r < 4; ++r)
            atomicAdd(&S[(size_t)(j0 + g4*4 + r) * F2D + w*32 + nt*16 + l15], acc[nt][r]);
}

// ---------------- K3: apply Wf3 to summed h2 ----------------
// 256 blocks x 256 threads, 2 j per block.
__global__ void k3_msg(const float* __restrict__ S,
                       const float* __restrict__ Wf3,
                       const float* __restrict__ bf3,
                       float* __restrict__ SM) {
    __shared__ float sl[2][F2D];
    const int t = threadIdx.x;
    const int j0 = blockIdx.x * 2;
    for (int q = t; q < 2 * F2D; q += 256)
        sl[q >> 8][q & 255] = S[(size_t)(j0 + (q >> 8)) * F2D + (q & 255)];
    __syncthreads();

    const int m = t & 127;
    const int jl = t >> 7;
    const float* wr = Wf3 + m * F2D;
    float acc = (float)NN * bf3[m];
    for (int k = 0; k < F2D; k += 4) {
        float4_t wv = *(const float4_t*)(wr + k);
        const float* sp = &sl[jl][k];
        acc += wv[0]*sp[0] + wv[1]*sp[1] + wv[2]*sp[2] + wv[3]*sp[3];
    }
    SM[(size_t)(j0 + jl) * MSGD + m] = acc;
}

// ---------------- K4: fused tail ----------------
// 128 blocks x 256 threads, 4 rows each. All fp32.
__global__ void k4_tail(const float* __restrict__ x,
                        const float* __restrict__ h0,
                        const float* __restrict__ c0,
                        const float* __restrict__ SM,
                        const float* __restrict__ Wg1, const float* __restrict__ bg1,
                        const float* __restrict__ Wg2, const float* __restrict__ bg2,
                        const float* __restrict__ Wg3, const float* __restrict__ bg3,
                        const float* __restrict__ W_ih, const float* __restrict__ W_hh,
                        const float* __restrict__ b_ih, const float* __restrict__ b_hh,
                        const float* __restrict__ Wo1, const float* __restrict__ bo1,
                        const float* __restrict__ Wo2, const float* __restrict__ bo2,
                        float* __restrict__ out,
                        float* __restrict__ hid_out,
                        float* __restrict__ h_out,
                        float* __restrict__ c_out) {
    __shared__ float gin[4][256];
    __shared__ float g1b[4][256];
    __shared__ float g2b[4][256];
    __shared__ float igb[4][128];
    __shared__ float gates[4][512];
    __shared__ float h0b[4][128];
    __shared__ float c0b[4][128];
    __shared__ float hb[4][128];
    __shared__ float o1b[4][256];

    const int t = threadIdx.x;
    const int r0 = blockIdx.x * 4;

    for (int q = t; q < 4 * 128; q += 256) {
        int r = q >> 7, k = q & 127;
        int row = r0 + r;
        gin[r][k]       = x[row * HH + k];
        gin[r][128 + k] = SM[row * MSGD + k];
        h0b[r][k]       = h0[row * HH + k];
        c0b[r][k]       = c0[row * HH + k];
    }
    __syncthreads();

    // g1 = relu(g_in @ Wg1.T + bg1): neuron t, 4 rows
    {
        float a[4];
        const float b = bg1[t];
#pragma unroll
        for (int r = 0; r < 4; ++r) a[r] = b;
        const float* wr = Wg1 + t * 256;
        for (int k = 0; k < 256; k += 4) {
            float4_t wv = *(const float4_t*)(wr + k);
#pragma unroll
            for (int r = 0; r < 4; ++r) {
                const float* gp = &gin[r][k];
                a[r] += wv[0]*gp[0] + wv[1]*gp[1] + wv[2]*gp[2] + wv[3]*gp[3];
            }
        }
#pragma unroll
        for (int r = 0; r < 4; ++r) g1b[r][t] = fmaxf(a[r], 0.0f);
    }
    __syncthreads();

    // g2 = relu(g1 @ Wg2.T + bg2)
    {
        float a[4];
        const float b = bg2[t];
#pragma unroll
        for (int r = 0; r < 4; ++r) a[r] = b;
        const float* wr = Wg2 + t * 256;
        for (int k = 0; k < 256; k += 4) {
            float4_t wv = *(const float4_t*)(wr + k);
#pragma unroll
            for (int r = 0; r < 4; ++r) {
                const float* gp = &g1b[r][k];
                a[r] += wv[0]*gp[0] + wv[1]*gp[1] + wv[2]*gp[2] + wv[3]*gp[3];
            }
        }
#pragma unroll
        for (int r = 0; r < 4; ++r) g2b[r][t] = fmaxf(a[r], 0.0f);
    }
    __syncthreads();

    // input_g = g2 @ Wg3.T + bg3: 128 neurons x 4 rows -> 2 outputs/thread
    {
        const int n = t & 127;
        const int rb = (t >> 7) * 2;
        float a[2];
        const float b = bg3[n];
        a[0] = b; a[1] = b;
        const float* wr = Wg3 + n * 256;
        for (int k = 0; k < 256; k += 4) {
            float4_t wv = *(const float4_t*)(wr + k);
#pragma unroll
            for (int rr = 0; rr < 2; ++rr) {
                const float* gp = &g2b[rb + rr][k];
                a[rr] += wv[0]*gp[0] + wv[1]*gp[1] + wv[2]*gp[2] + wv[3]*gp[3];
            }
        }
        igb[rb][n] = a[0];
        igb[rb + 1][n] = a[1];
    }
    __syncthreads();

    // gates = input_g @ W_ih.T + b_ih + h0 @ W_hh.T + b_hh
    {
#pragma unroll
        for (int hf = 0; hf < 2; ++hf) {
            const int n = t + hf * 256;
            float a[4];
            const float b = b_ih[n] + b_hh[n];
#pragma unroll
            for (int r = 0; r < 4; ++r) a[r] = b;
            const float* wi = W_ih + n * 128;
            const float* wh = W_hh + n * 128;
            for (int k = 0; k < 128; k += 4) {
                float4_t wv  = *(const float4_t*)(wi + k);
                float4_t wv2 = *(const float4_t*)(wh + k);
#pragma unroll
                for (int r = 0; r < 4; ++r) {
                    const float* ip = &igb[r][k];
                    const float* hp = &h0b[r][k];
                    a[r] += wv[0]*ip[0] + wv[1]*ip[1] + wv[2]*ip[2] + wv[3]*ip[3];
                    a[r] += wv2[0]*hp[0] + wv2[1]*hp[1] + wv2[2]*hp[2] + wv2[3]*hp[3];
                }
            }
#pragma unroll
            for (int r = 0; r < 4; ++r) gates[r][n] = a[r];
        }
    }
    __syncthreads();

    // LSTM elementwise
    {
        const int n = t & 127;
        const int rb = (t >> 7) * 2;
#pragma unroll
        for (int rr = 0; rr < 2; ++rr) {
            const int r = rb + rr;
            const int row = r0 + r;
            float ig_ = sigmoidf_(gates[r][n]);
            float fg  = sigmoidf_(gates[r][128 + n]);
            float gg  = tanhf(gates[r][256 + n]);
            float og  = sigmoidf_(gates[r][384 + n]);
            float c = fg * c0b[r][n] + ig_ * gg;
            float h = og * tanhf(c);
            hb[r][n] = h;
            hid_out[row * HH + n] = h;
            h_out[row * HH + n]   = h;
            c_out[row * HH + n]   = c;
        }
    }
    __syncthreads();

    // o1 = relu(h @ Wo1.T + bo1)
    {
        float a[4];
        const float b = bo1[t];
#pragma unroll
        for (int r = 0; r < 4; ++r) a[r] = b;
        const float* wr = Wo1 + t * 128;
        for (int k = 0; k < 128; k += 4) {
            float4_t wv = *(const float4_t*)(wr + k);
#pragma unroll
            for (int r = 0; r < 4; ++r) {
                const float* hp = &hb[r][k];
                a[r] += wv[0]*hp[0] + wv[1]*hp[1] + wv[2]*hp[2] + wv[3]*hp[3];
            }
        }
#pragma unroll
        for (int r = 0; r < 4; ++r) o1b[r][t] = fmaxf(a[r], 0.0f);
    }
    __syncthreads();

    // out = o1 @ Wo2.T + bo2
    {
        const int n = t & 63;
        const int r = t >> 6;
        const int row = r0 + r;
        float a = bo2[n];
        const float* wr = Wo2 + n * 256;
        for (int k = 0; k < 256; k += 4) {
            float4_t wv = *(const float4_t*)(wr + k);
            const float* op = &o1b[r][k];
            a += wv[0]*op[0] + wv[1]*op[1] + wv[2]*op[2] + wv[3]*op[3];
        }
        out[row * OUTD + n] = a;
    }
}

// ---------------------------------------------------------------------------
extern "C" void kernel_launch(void* const* d_in, const int* in_sizes, int n_in,
                              void* d_out, int out_size, void* d_ws, size_t ws_size,
                              hipStream_t stream) {
    const float* x      = (const float*)d_in[0];
    const float* hidden = (const float*)d_in[1];
    const float* h0     = (const float*)d_in[2];
    const float* c0     = (const float*)d_in[3];
    const float* Wf1    = (const float*)d_in[4];
    const float* bf1    = (const float*)d_in[5];
    const float* Wf2    = (const float*)d_in[6];
    const float* bf2    = (const float*)d_in[7];
    const float* Wf3    = (const float*)d_in[8];
    const float* bf3    = (const float*)d_in[9];
    const float* Wg1    = (const float*)d_in[10];
    const float* bg1    = (const float*)d_in[11];
    const float* Wg2    = (const float*)d_in[12];
    const float* bg2    = (const float*)d_in[13];
    const float* Wg3    = (const float*)d_in[14];
    const float* bg3    = (const float*)d_in[15];
    const float* W_ih   = (const float*)d_in[16];
    const float* W_hh   = (const float*)d_in[17];
    const float* b_ih   = (const float*)d_in[18];
    const float* b_hh   = (const float*)d_in[19];
    const float* Wo1    = (const float*)d_in[20];
    const float* bo1    = (const float*)d_in[21];
    const float* Wo2    = (const float*)d_in[22];
    const float* bo2    = (const float*)d_in[23];

    // workspace layout (bytes)
    char* ws = (char*)d_ws;
    float*  A32  = (float*)(ws + 0);           // 512*256*4 = 512K
    float*  B32  = (float*)(ws + 524288);      // 512K
    half_t* Whi  = (half_t*)(ws + 1048576);    // 128K
    half_t* Wlo  = (half_t*)(ws + 1179648);    // 128K
    float*  S    = (float*)(ws + 1310720);     // 512K
    float*  SM   = (float*)(ws + 1835008);     // 256K

    float* outp  = (float*)d_out;              // [512,64]
    float* hid1  = (float*)d_out + 32768;      // hidden_new [512,128]
    float* hid2  = (float*)d_out + 98304;      // hidden_new[None]
    float* cout  = (float*)d_out + 163840;     // c_new[None]

    hipMemsetAsync(S, 0, (size_t)NN * F2D * sizeof(float), stream);

    k1_proj<<<dim3(128), dim3(256), 0, stream>>>(hidden, Wf1, bf1, Wf2,
                                                 A32, B32, Whi, Wlo);

    k2_pairwise<<<dim3(8, 32), dim3(512), 0, stream>>>(A32, B32, Whi, Wlo, bf2, S);

    k3_msg<<<dim3(256), dim3(256), 0, stream>>>(S, Wf3, bf3, SM);

    k4_tail<<<dim3(128), dim3(256), 0, stream>>>(x, h0, c0, SM,
                                                 Wg1, bg1, Wg2, bg2, Wg3, bg3,
                                                 W_ih, W_hh, b_ih, b_hh,
                                                 Wo1, bo1, Wo2, bo2,
                                                 outp, hid1, hid2, cout);
}